// Round 9
// baseline (222.491 us; speedup 1.0000x reference)
//
#include <hip/hip_runtime.h>
#include <cstddef>

#define N_NODES 12288
#define SIG     2048
#define C1N     16
#define L1N     1024
#define C2N     32
#define F0      64
#define F1      128
#define NEDGE   196608
#define NGRAPH  1024

#define C1S     536      // u16 row stride of phase c1 buffer (268 words; %32=12 -> 2-way banks)
#define C1WRD   268      // word stride
#define XW_N    1060     // u32 words of staged x: u16 idx i = x[i-8]

typedef float    f32x4 __attribute__((ext_vector_type(4)));
typedef _Float16 f16x8 __attribute__((ext_vector_type(8)));

__device__ __forceinline__ unsigned short f16_bits(float f) {
    union { _Float16 h; unsigned short u; } c; c.h = (_Float16)f; return c.u;
}
__device__ __forceinline__ unsigned f16_pk(float a, float b) {
    return (unsigned)f16_bits(a) | ((unsigned)f16_bits(b) << 16);
}

// ---------------------------------------------------------------- encoder
// one block (256 threads = 4 waves) per node. BOTH convs on MFMA.
// 2-phase c1 ping-pong (512 conv2 outputs/phase): LDS ~22KB -> 7 blocks/CU
// (R8 was 38.4KB -> 4 blocks, 30% stall at 41% occupancy).
// conv1 as GEMM (K=32, taps at k=1..7): x staged once as fp16 pairs in xw.
// conv2 as GEMM with TAP-PAIRED K: K=32 = 16ch x 2taps, pairs (0,1),(2,3),(4,-).
//   k = 2*icl + tp -> lane j: icl=4*hi8+(j>>1), tp=j&1; B value =
//   c1[icl][2q+2kt+tp - (512ph-2) ... ] -> word (qloc+kt) of row icl: ONE
//   ds_read_b32 per (jj,kt,ntl), all addresses = bq_base + compile-time imm.
// mfma_f32_16x16x32_f16 (m89/m91): A row=l&15,k=(l>>4)*8+j; B col=l&15,same k;
//   C/D col=l&15, row=(l>>4)*4+reg.
// Lessons: R2 no min-waves hint; R4 q enters B addr once; R5 no stride-4 reads;
//   R7 barriers are cheap only when enough blocks are resident (hence 7/CU here).
__global__ __launch_bounds__(256) void k_encoder(
    const float* __restrict__ x_raw,
    const float* __restrict__ conv1_w, const float* __restrict__ conv1_b,
    const float* __restrict__ conv2_w, const float* __restrict__ conv2_b,
    const float* __restrict__ lin_w,   const float* __restrict__ lin_b,
    float* __restrict__ h0)
{
    __shared__ __align__(16) unsigned xw[XW_N];              // fp16-pair staged x
    __shared__ __align__(16) unsigned short c1h[C1N][C1S];   // fp16 c1, phase-local slots
    __shared__ float wmsum[4][C2N];
    __shared__ float mean_s[C2N];

    const int tid  = threadIdx.x;
    const int node = blockIdx.x;
    const int lane = tid & 63;
    const int wv   = tid >> 6;
    const int colL = lane & 15;
    const int hi8  = lane >> 4;
    const float* xrow = x_raw + (size_t)node * SIG;

    // ---- stage x as fp16 pairs: thread t covers x[8t..8t+7] -> words 4t+4..4t+7
    {
        float4 xa = ((const float4*)xrow)[2 * tid];
        float4 xb = ((const float4*)xrow)[2 * tid + 1];
        uint4 w;
        w.x = f16_pk(xa.x, xa.y); w.y = f16_pk(xa.z, xa.w);
        w.z = f16_pk(xb.x, xb.y); w.w = f16_pk(xb.z, xb.w);
        *(uint4*)&xw[4 * tid + 4] = w;
    }
    if (tid < 4)  xw[tid] = 0u;            // x[-8..-1]
    if (tid < 32) xw[1028 + tid] = 0u;     // x[2048..] tail pad (reads reach word 1054)

    // ---- conv1 A fragment: k=1..7 hold taps 0..6 (hi8==0 lanes only)
    f16x8 w1A;
    #pragma unroll
    for (int j = 0; j < 8; ++j) w1A[j] = (_Float16)0.f;
    if (hi8 == 0) {
        #pragma unroll
        for (int j = 1; j < 8; ++j) w1A[j] = (_Float16)conv1_w[colL * 7 + (j - 1)];
    }
    float bias1[4];
    #pragma unroll
    for (int r = 0; r < 4; ++r) bias1[r] = conv1_b[hi8 * 4 + r];

    // ---- conv2 A fragments, tap-paired: 2 m-tiles x 3 k-tiles
    f16x8 wA[2][3];
    #pragma unroll
    for (int mt = 0; mt < 2; ++mt) {
        const int oc = mt * 16 + colL;
        #pragma unroll
        for (int kt = 0; kt < 3; ++kt) {
            #pragma unroll
            for (int j = 0; j < 8; ++j) {
                const int icl = 4 * hi8 + (j >> 1);
                const int tap = 2 * kt + (j & 1);
                wA[mt][kt][j] = (_Float16)((tap < 5) ? conv2_w[oc * 80 + icl * 5 + tap] : 0.f);
            }
        }
    }
    float bias2[2][4];
    #pragma unroll
    for (int mt = 0; mt < 2; ++mt)
        #pragma unroll
        for (int r = 0; r < 4; ++r)
            bias2[mt][r] = conv2_b[mt * 16 + hi8 * 4 + r];

    float msumr[2][4];
    #pragma unroll
    for (int mt = 0; mt < 2; ++mt)
        #pragma unroll
        for (int r = 0; r < 4; ++r) msumr[mt][r] = 0.f;

    // conv2 B base address (phase-independent): word = hi8*1072 + qloc(+imm)
    const unsigned* bq_base = (const unsigned*)&c1h[0][0]
                              + hi8 * (4 * C1WRD) + 64 * wv + colL;

    __syncthreads();   // xw ready

    // ---- 2 phases of 512 conv2 output positions (528 c1 slots) each
    #pragma unroll 1
    for (int ph = 0; ph < 2; ++ph) {
        const int Pb = 512 * ph - 2;           // slot s holds c1 position Pb + s

        // conv1: 33 pos-tiles of 16 (1 halo); wave wv does T = wv, wv+4, ...
        for (int T = wv; T < 33; T += 4) {
            const int slot  = 16 * T + colL;
            const int wbase = 512 * ph + 16 * T + colL + 4 * hi8;
            union { unsigned u[4]; f16x8 v; } Bx;
            #pragma unroll
            for (int u = 0; u < 4; ++u) Bx.u[u] = xw[wbase + u];
            f32x4 a;
            a[0] = bias1[0]; a[1] = bias1[1]; a[2] = bias1[2]; a[3] = bias1[3];
            a = __builtin_amdgcn_mfma_f32_16x16x32_f16(w1A, Bx.v, a, 0, 0, 0);
            const bool val = (unsigned)(Pb + slot) < (unsigned)L1N;
            #pragma unroll
            for (int r = 0; r < 4; ++r)
                c1h[hi8 * 4 + r][slot] = f16_bits(val ? fmaxf(a[r], 0.f) : 0.f);
        }
        __syncthreads();   // c1 phase ready

        // conv2: wave wv covers qloc = 64wv..64wv+63 (nt = 2*nt2+ntl)
        #pragma unroll 1
        for (int nt2 = 0; nt2 < 2; ++nt2) {
            const unsigned* bq2 = bq_base + 32 * nt2;
            f32x4 acc[2][2];   // [ntl][mt]
            #pragma unroll
            for (int ntl = 0; ntl < 2; ++ntl)
                #pragma unroll
                for (int mt = 0; mt < 2; ++mt) {
                    acc[ntl][mt][0] = bias2[mt][0]; acc[ntl][mt][1] = bias2[mt][1];
                    acc[ntl][mt][2] = bias2[mt][2]; acc[ntl][mt][3] = bias2[mt][3];
                }
            #pragma unroll
            for (int kt = 0; kt < 3; ++kt) {
                #pragma unroll
                for (int ntl = 0; ntl < 2; ++ntl) {
                    union { unsigned u[4]; f16x8 v; } B;
                    #pragma unroll
                    for (int jj = 0; jj < 4; ++jj)
                        B.u[jj] = bq2[jj * C1WRD + 16 * ntl + kt];   // imm offsets
                    #pragma unroll
                    for (int mt = 0; mt < 2; ++mt)
                        acc[ntl][mt] = __builtin_amdgcn_mfma_f32_16x16x32_f16(wA[mt][kt], B.v, acc[ntl][mt], 0, 0, 0);
                }
            }
            #pragma unroll
            for (int ntl = 0; ntl < 2; ++ntl)
                #pragma unroll
                for (int mt = 0; mt < 2; ++mt)
                    #pragma unroll
                    for (int r = 0; r < 4; ++r)
                        msumr[mt][r] += fmaxf(acc[ntl][mt][r], 0.f);
        }
        __syncthreads();   // before next phase overwrites c1h
    }

    // ---- reduce over the 16 columns within each 16-lane group
    #pragma unroll
    for (int mt = 0; mt < 2; ++mt)
        #pragma unroll
        for (int r = 0; r < 4; ++r) {
            float s = msumr[mt][r];
            s += __shfl_xor(s, 1);
            s += __shfl_xor(s, 2);
            s += __shfl_xor(s, 4);
            s += __shfl_xor(s, 8);
            msumr[mt][r] = s;
        }
    if (colL == 0) {
        #pragma unroll
        for (int mt = 0; mt < 2; ++mt)
            #pragma unroll
            for (int r = 0; r < 4; ++r)
                wmsum[wv][mt * 16 + hi8 * 4 + r] = msumr[mt][r];
    }
    __syncthreads();

    if (tid < C2N) {
        float s = wmsum[0][tid] + wmsum[1][tid] + wmsum[2][tid] + wmsum[3][tid];
        mean_s[tid] = s * (1.f / 512.f);
    }
    __syncthreads();

    // ---- linear 32 -> 64
    if (tid < F0) {
        float a = lin_b[tid];
        #pragma unroll
        for (int ic = 0; ic < C2N; ++ic)
            a = fmaf(mean_s[ic], lin_w[ic * F0 + tid], a);
        h0[(size_t)node * F0 + tid] = a;
    }
}

// ---------------------------------------------------------------- degree + graph-node count (fused)
__global__ __launch_bounds__(256) void k_count_cnt(const int* __restrict__ dst,
                                                   const int* __restrict__ batch,
                                                   int* __restrict__ deg,
                                                   float* __restrict__ cnt)
{
    const int bid = blockIdx.x;
    if (bid < NEDGE / 256) {
        int e = bid * 256 + threadIdx.x;
        atomicAdd(&deg[dst[e]], 1);
    } else {
        int n = (bid - NEDGE / 256) * 256 + threadIdx.x;
        atomicAdd(&cnt[batch[n]], 1.f);
    }
}

// ---------------------------------------------------------------- scan + dis/invd (1 block, shuffle-based)
__global__ __launch_bounds__(1024) void k_scan(const int* __restrict__ deg,
                                               int* __restrict__ rowptr,
                                               int* __restrict__ cursor,
                                               float* __restrict__ dis,
                                               float* __restrict__ invd)
{
    __shared__ int wtot[16];
    const int t = threadIdx.x;
    const int lane = t & 63, wvid = t >> 6;
    int d[12]; int s = 0;
    #pragma unroll
    for (int m = 0; m < 12; ++m) { d[m] = deg[12 * t + m]; s += d[m]; }
    const int mysum = s;
    #pragma unroll
    for (int off = 1; off < 64; off <<= 1) {
        int u = __shfl_up(s, off);
        if (lane >= off) s += u;
    }
    if (lane == 63) wtot[wvid] = s;
    __syncthreads();
    if (t < 16) {
        int v = wtot[t];
        #pragma unroll
        for (int off = 1; off < 16; off <<= 1) {
            int u = __shfl_up(v, off);
            if (t >= off) v += u;
        }
        wtot[t] = v;
    }
    __syncthreads();
    int run = (wvid ? wtot[wvid - 1] : 0) + (s - mysum);   // block-exclusive prefix
    if (t == 0) rowptr[0] = 0;
    #pragma unroll
    for (int m = 0; m < 12; ++m) {
        const int i = 12 * t + m;
        cursor[i] = run;
        run += d[m];
        rowptr[i + 1] = run;
        float df = (float)(d[m] + 1);
        dis[i]  = rsqrtf(df);
        invd[i] = 1.f / df;
    }
}

// ---------------------------------------------------------------- CSR scatter
__global__ __launch_bounds__(256) void k_scatter(const int* __restrict__ src,
                                                 const int* __restrict__ dst,
                                                 int* __restrict__ cursor,
                                                 int* __restrict__ csr)
{
    int e = blockIdx.x * 256 + threadIdx.x;
    if (e < NEDGE) {
        int d = dst[e];
        int idx = atomicAdd(&cursor[d], 1);
        csr[idx] = src[e];
    }
}

// ---------------------------------------------------------------- aggregation BEFORE transform (pull)
// agg[n] = invd[n]*h[n] + sum_s dis[s]*dis[n]*h[s]
template <int F>
__global__ __launch_bounds__(256) void k_pull_a(
    const float* __restrict__ h, const int* __restrict__ rowptr,
    const int* __restrict__ csr, const float* __restrict__ dis,
    const float* __restrict__ invd, float* __restrict__ agg)
{
    const int npb = 256 / F;
    const int n = blockIdx.x * npb + threadIdx.x / F;
    const int f = threadIdx.x & (F - 1);
    const float dn = dis[n];
    float a0 = h[(size_t)n * F + f] * invd[n];
    float a1 = 0.f, a2 = 0.f, a3 = 0.f;
    int e = rowptr[n];
    const int e1 = rowptr[n + 1];
    for (; e + 3 < e1; e += 4) {
        int s0 = csr[e], s1 = csr[e + 1], s2 = csr[e + 2], s3 = csr[e + 3];
        a0 = fmaf(h[(size_t)s0 * F + f], dis[s0] * dn, a0);
        a1 = fmaf(h[(size_t)s1 * F + f], dis[s1] * dn, a1);
        a2 = fmaf(h[(size_t)s2 * F + f], dis[s2] * dn, a2);
        a3 = fmaf(h[(size_t)s3 * F + f], dis[s3] * dn, a3);
    }
    for (; e < e1; ++e) {
        int s0 = csr[e];
        a0 = fmaf(h[(size_t)s0 * F + f], dis[s0] * dn, a0);
    }
    agg[(size_t)n * F + f] = (a0 + a1) + (a2 + a3);
}

// ---------------------------------------------------------------- agg @ W + bias + relu (+pool)
template <int K, int POOL>
__global__ __launch_bounds__(256) void k_gemm_f(
    const float* __restrict__ in, const float* __restrict__ W,
    const float* __restrict__ bvec, float* __restrict__ out,
    const int* __restrict__ batch, float* __restrict__ pooled)
{
    __shared__ float hs[8][K];
    const int tid  = threadIdx.x;
    const int n0   = blockIdx.x * 8;
    const int j    = tid & 127;
    const int half = tid >> 7;

    #pragma unroll
    for (int it = 0; it < 8 * K / 256; ++it) {
        int idx = it * 256 + tid;
        int nn = idx / K, kk = idx & (K - 1);
        hs[nn][kk] = in[(size_t)(n0 + nn) * K + kk];
    }
    __syncthreads();

    float a[4];
    #pragma unroll
    for (int c = 0; c < 4; ++c) a[c] = bvec[j];

    for (int k4 = 0; k4 < K; k4 += 4) {
        float w0 = W[(k4 + 0) * F1 + j];
        float w1 = W[(k4 + 1) * F1 + j];
        float w2 = W[(k4 + 2) * F1 + j];
        float w3 = W[(k4 + 3) * F1 + j];
        #pragma unroll
        for (int c = 0; c < 4; ++c) {
            float4 hv = *(const float4*)&hs[half * 4 + c][k4];
            a[c] = fmaf(hv.x, w0, a[c]);
            a[c] = fmaf(hv.y, w1, a[c]);
            a[c] = fmaf(hv.z, w2, a[c]);
            a[c] = fmaf(hv.w, w3, a[c]);
        }
    }
    #pragma unroll
    for (int c = 0; c < 4; ++c) {
        float r = fmaxf(a[c], 0.f);
        int n = n0 + half * 4 + c;
        if (POOL) atomicAdd(&pooled[(size_t)batch[n] * F1 + j], r);
        else      out[(size_t)n * F1 + j] = r;
    }
}

// ---------------------------------------------------------------- final FC 128 -> 5
__global__ __launch_bounds__(128) void k_final(const float* __restrict__ pooled,
                                               const float* __restrict__ cnt,
                                               const float* __restrict__ fc_w,
                                               const float* __restrict__ fc_b,
                                               float* __restrict__ out)
{
    __shared__ float ps[F1];
    const int g = blockIdx.x, tid = threadIdx.x;
    float inv = 1.f / fmaxf(cnt[g], 1.f);
    ps[tid] = pooled[g * F1 + tid] * inv;
    __syncthreads();
    if (tid < 5) {
        float a = fc_b[tid];
        for (int f = 0; f < F1; ++f) a = fmaf(ps[f], fc_w[f * 5 + tid], a);
        out[g * 5 + tid] = a;
    }
}

// ---------------------------------------------------------------- launch
extern "C" void kernel_launch(void* const* d_in, const int* in_sizes, int n_in,
                              void* d_out, int out_size, void* d_ws, size_t ws_size,
                              hipStream_t stream)
{
    const float* x_raw = (const float*)d_in[0];
    const float* c1w   = (const float*)d_in[1];
    const float* c1b   = (const float*)d_in[2];
    const float* c2w   = (const float*)d_in[3];
    const float* c2b   = (const float*)d_in[4];
    const float* lw    = (const float*)d_in[5];
    const float* lb    = (const float*)d_in[6];
    const float* g1w   = (const float*)d_in[7];
    const float* g1b   = (const float*)d_in[8];
    const float* g2w   = (const float*)d_in[9];
    const float* g2b   = (const float*)d_in[10];
    const float* fcw   = (const float*)d_in[11];
    const float* fcb   = (const float*)d_in[12];
    const int*   ei    = (const int*)d_in[13];
    const int*   batch = (const int*)d_in[14];
    const int* src = ei;
    const int* dst = ei + NEDGE;

    float* ws = (float*)d_ws;
    float* h0     = ws + 0;                    // 786432  (12288 x 64)
    float* agg1   = ws + 786432;               // 786432
    float* h1     = ws + 1572864;              // 1572864 (12288 x 128)
    float* agg2   = ws + 3145728;              // 1572864
    float* dis    = ws + 4718592;              // 12288
    float* invd   = ws + 4730880;              // 12288
    float* pooled = ws + 4743168;              // 131072
    float* cnt    = ws + 4874240;              // 1024
    int*   deg    = (int*)(ws + 4875264);      // 12288
    int*   rowptr = (int*)(ws + 4887552);      // 12289 (+pad)
    int*   cursor = (int*)(ws + 4899844);      // 12288
    int*   csr    = (int*)(ws + 4912132);      // 196608

    float* out = (float*)d_out;

    hipMemsetAsync(deg, 0, N_NODES * sizeof(int), stream);
    hipMemsetAsync(pooled, 0, (size_t)(NGRAPH * F1 + NGRAPH) * sizeof(float), stream);

    k_encoder<<<N_NODES, 256, 0, stream>>>(x_raw, c1w, c1b, c2w, c2b, lw, lb, h0);
    k_count_cnt<<<NEDGE / 256 + N_NODES / 256, 256, 0, stream>>>(dst, batch, deg, cnt);
    k_scan<<<1, 1024, 0, stream>>>(deg, rowptr, cursor, dis, invd);
    k_scatter<<<NEDGE / 256, 256, 0, stream>>>(src, dst, cursor, csr);

    // GCN layer 1: aggregate (64-dim) then transform
    k_pull_a<F0><<<N_NODES / 4, 256, 0, stream>>>(h0, rowptr, csr, dis, invd, agg1);
    k_gemm_f<F0, 0><<<N_NODES / 8, 256, 0, stream>>>(agg1, g1w, g1b, h1, batch, pooled);

    // GCN layer 2: aggregate (128-dim) then transform + fused pool
    k_pull_a<F1><<<N_NODES / 2, 256, 0, stream>>>(h1, rowptr, csr, dis, invd, agg2);
    k_gemm_f<F1, 1><<<N_NODES / 8, 256, 0, stream>>>(agg2, g2w, g2b, nullptr, batch, pooled);

    k_final<<<NGRAPH, 128, 0, stream>>>(pooled, cnt, fcw, fcb, out);
}

// Round 11
// 192.707 us; speedup vs baseline: 1.1546x; 1.1546x over previous
//
#include <hip/hip_runtime.h>
#include <cstddef>

#define N_NODES 12288
#define SIG     2048
#define C1N     16
#define L1N     1024
#define C2N     32
#define F0      64
#define F1      128
#define NEDGE   196608
#define NGRAPH  1024

typedef float    f32x4 __attribute__((ext_vector_type(4)));
typedef _Float16 f16x8 __attribute__((ext_vector_type(8)));
typedef __fp16   fp16x2_raw __attribute__((ext_vector_type(2)));   // cvt_pkrtz native type

__device__ __forceinline__ unsigned short f16_bits(float f) {
    union { _Float16 h; unsigned short u; } c; c.h = (_Float16)f; return c.u;
}
__device__ __forceinline__ unsigned f16_pk(float a, float b) {   // RTN pack
    return (unsigned)f16_bits(a) | ((unsigned)f16_bits(b) << 16);
}
__device__ __forceinline__ unsigned pkrtz(float a, float b) {    // RTZ pack, 1 inst
    union { fp16x2_raw h; unsigned u; } c;
    c.h = __builtin_amdgcn_cvt_pkrtz(a, b);
    return c.u;
}

// ---------------------------------------------------------------- encoder
// one block (256 threads = 4 waves) per node; ZERO hot barriers.
// Each WAVE wq owns conv2 outputs q in [128wq, 128wq+128), processed in 4
// sub-phases of 32. Per sub-phase the wave: (conv1 MFMA -> its private
// transposed c1 region) then (conv2 MFMA from it). Intra-wave LDS write->read
// needs no __syncthreads (same-wave DS ops are in-order; lgkmcnt enforced by
// compiler). Barrier evidence: R7 8 barriers=182us, R8 2=141, R9 4=148.
// c1t TRANSPOSED [slot][20 u16 (16ch+pad)]: conv1 C-frag = 4 consecutive oc
//   -> one ds_write_b64 (2x cvt_pkrtz); conv2 B-frag = 2x ds_read_b64
//   (k=8*hi8+j -> ic=4*hi8+(j&3), tap=2*kt+(j>>2); slot=2*ql+2*kt+(j>>2)).
// conv1 as GEMM (K=32, taps at k=1..7): x staged per-wave as fp16 pairs
//   (xu16[i]=x[i-8]); B-frag = 4 ds_read_b32 at word 2qb+16T+colL+4hi8.
// mfma_f32_16x16x32_f16 (m89/m91): A row=l&15,k=(l>>4)*8+j; B col=l&15,same k;
//   C/D col=l&15, row=(l>>4)*4+reg.
// Lessons: R2 no min-waves hint; R4 pos enters addr once; R5 no stride-4 reads;
//   R9 barriers dominate over instruction count; R10 cvt_pkrtz returns __fp16x2.
__global__ __launch_bounds__(256) void k_encoder(
    const float* __restrict__ x_raw,
    const float* __restrict__ conv1_w, const float* __restrict__ conv1_b,
    const float* __restrict__ conv2_w, const float* __restrict__ conv2_b,
    const float* __restrict__ lin_w,   const float* __restrict__ lin_b,
    float* __restrict__ h0)
{
    __shared__ __align__(16) unsigned xw[1056];      // fp16-pair x, global coords
    __shared__ __align__(16) unsigned c1t[4 * 800];  // per-wave [80 slot][10 words]
    __shared__ float wmsum[4][C2N];
    __shared__ float mean_s[C2N];

    const int tid  = threadIdx.x;
    const int node = blockIdx.x;
    const int lane = tid & 63;
    const int wq   = tid >> 6;
    const int colL = lane & 15;
    const int hi8  = lane >> 4;
    const float* xrow = x_raw + (size_t)node * SIG;

    // ---- stage this wave's xw slice: words [256wq, 256wq+288) (RTN cvt)
    #pragma unroll
    for (int ii = 0; ii < 2; ++ii) {
        int i = lane + 64 * ii;
        if (i < 72) {
            int xb = 512 * wq + 8 * i - 8;
            float v[8];
            if (xb >= 0 && xb + 8 <= SIG) {
                float4 xa = *(const float4*)(xrow + xb);
                float4 xc = *(const float4*)(xrow + xb + 4);
                v[0] = xa.x; v[1] = xa.y; v[2] = xa.z; v[3] = xa.w;
                v[4] = xc.x; v[5] = xc.y; v[6] = xc.z; v[7] = xc.w;
            } else {
                #pragma unroll
                for (int t = 0; t < 8; ++t) {
                    int xi = xb + t;
                    v[t] = ((unsigned)xi < (unsigned)SIG) ? xrow[xi] : 0.f;
                }
            }
            uint4 w4;
            w4.x = f16_pk(v[0], v[1]); w4.y = f16_pk(v[2], v[3]);
            w4.z = f16_pk(v[4], v[5]); w4.w = f16_pk(v[6], v[7]);
            *(uint4*)&xw[256 * wq + 4 * i] = w4;
        }
    }

    // ---- conv1 A fragment: k=1..7 hold taps 0..6 (hi8==0 lanes only)
    f16x8 w1A;
    #pragma unroll
    for (int j = 0; j < 8; ++j) w1A[j] = (_Float16)0.f;
    if (hi8 == 0) {
        #pragma unroll
        for (int j = 1; j < 8; ++j) w1A[j] = (_Float16)conv1_w[colL * 7 + (j - 1)];
    }
    float bias1[4];
    #pragma unroll
    for (int r = 0; r < 4; ++r) bias1[r] = conv1_b[hi8 * 4 + r];

    // ---- conv2 A fragments: 2 m-tiles x 3 k-tiles; ic=4hi8+(j&3), tap=2kt+(j>>2)
    f16x8 wA[2][3];
    #pragma unroll
    for (int mt = 0; mt < 2; ++mt) {
        const int oc = mt * 16 + colL;
        #pragma unroll
        for (int kt = 0; kt < 3; ++kt) {
            #pragma unroll
            for (int j = 0; j < 8; ++j) {
                const int ic  = 4 * hi8 + (j & 3);
                const int tap = 2 * kt + (j >> 2);
                wA[mt][kt][j] = (_Float16)((tap < 5) ? conv2_w[oc * 80 + ic * 5 + tap] : 0.f);
            }
        }
    }
    float bias2[2][4];
    #pragma unroll
    for (int mt = 0; mt < 2; ++mt)
        #pragma unroll
        for (int r = 0; r < 4; ++r)
            bias2[mt][r] = conv2_b[mt * 16 + hi8 * 4 + r];

    float msumr[2][4];
    #pragma unroll
    for (int mt = 0; mt < 2; ++mt)
        #pragma unroll
        for (int r = 0; r < 4; ++r) msumr[mt][r] = 0.f;

    unsigned* cw = &c1t[wq * 800];            // this wave's c1 region (words)
    const int rb = 20 * colL + 2 * hi8;       // lane part of conv2 B word addr

    // ---- 4 sub-phases of 32 conv2 outputs; NO barriers anywhere in this loop
    #pragma unroll 1
    for (int sp = 0; sp < 4; ++sp) {
        const int xwb = 256 * wq + 64 * sp;   // = 2*qb

        // conv1: 5 pos-tiles of 16 -> transposed c1 (slot = 16T+colL, ch 4hi8..+3)
        #pragma unroll
        for (int T = 0; T < 5; ++T) {
            const int wbase = xwb + 16 * T + colL + 4 * hi8;
            union { unsigned u[4]; f16x8 v; } Bx;
            #pragma unroll
            for (int u = 0; u < 4; ++u) Bx.u[u] = xw[wbase + u];
            f32x4 a;
            a[0] = bias1[0]; a[1] = bias1[1]; a[2] = bias1[2]; a[3] = bias1[3];
            a = __builtin_amdgcn_mfma_f32_16x16x32_f16(w1A, Bx.v, a, 0, 0, 0);
            uint2 wr;
            wr.x = pkrtz(fmaxf(a[0], 0.f), fmaxf(a[1], 0.f));
            wr.y = pkrtz(fmaxf(a[2], 0.f), fmaxf(a[3], 0.f));
            *(uint2*)&cw[(16 * T + colL) * 10 + 2 * hi8] = wr;   // ds_write_b64
        }
        // boundary fix: zero c1 slots whose position is outside [0,1024)
        if (wq == 0 && sp == 0) {               // pos -2,-1 -> slots 0,1
            if (lane < 20) cw[lane] = 0u;
        }
        if (wq == 3 && sp == 3) {               // pos >= 1024 -> slots 66..79
            for (int k2 = lane; k2 < 140; k2 += 64) cw[660 + k2] = 0u;
        }

        // conv2: 2 n-tiles of 16 outputs (ql = 16nt+colL)
        #pragma unroll
        for (int nt = 0; nt < 2; ++nt) {
            f32x4 acc[2];
            #pragma unroll
            for (int mt = 0; mt < 2; ++mt) {
                acc[mt][0] = bias2[mt][0]; acc[mt][1] = bias2[mt][1];
                acc[mt][2] = bias2[mt][2]; acc[mt][3] = bias2[mt][3];
            }
            #pragma unroll
            for (int kt = 0; kt < 3; ++kt) {
                union { uint2 u[2]; f16x8 v; } B;
                B.u[0] = *(const uint2*)&cw[rb + 320 * nt + 20 * kt];        // tap even
                B.u[1] = *(const uint2*)&cw[rb + 320 * nt + 20 * kt + 10];   // tap odd
                #pragma unroll
                for (int mt = 0; mt < 2; ++mt)
                    acc[mt] = __builtin_amdgcn_mfma_f32_16x16x32_f16(wA[mt][kt], B.v, acc[mt], 0, 0, 0);
            }
            #pragma unroll
            for (int mt = 0; mt < 2; ++mt)
                #pragma unroll
                for (int r = 0; r < 4; ++r)
                    msumr[mt][r] += fmaxf(acc[mt][r], 0.f);
        }
    }

    // ---- reduce over the 16 columns within each 16-lane group
    #pragma unroll
    for (int mt = 0; mt < 2; ++mt)
        #pragma unroll
        for (int r = 0; r < 4; ++r) {
            float s = msumr[mt][r];
            s += __shfl_xor(s, 1);
            s += __shfl_xor(s, 2);
            s += __shfl_xor(s, 4);
            s += __shfl_xor(s, 8);
            msumr[mt][r] = s;
        }
    if (colL == 0) {
        #pragma unroll
        for (int mt = 0; mt < 2; ++mt)
            #pragma unroll
            for (int r = 0; r < 4; ++r)
                wmsum[wq][mt * 16 + hi8 * 4 + r] = msumr[mt][r];
    }
    __syncthreads();   // the only block-wide barrier (cold path)

    if (tid < C2N) {
        float s = wmsum[0][tid] + wmsum[1][tid] + wmsum[2][tid] + wmsum[3][tid];
        mean_s[tid] = s * (1.f / 512.f);
    }
    __syncthreads();

    // ---- linear 32 -> 64
    if (tid < F0) {
        float a = lin_b[tid];
        #pragma unroll
        for (int ic = 0; ic < C2N; ++ic)
            a = fmaf(mean_s[ic], lin_w[ic * F0 + tid], a);
        h0[(size_t)node * F0 + tid] = a;
    }
}

// ---------------------------------------------------------------- degree + graph-node count (fused)
__global__ __launch_bounds__(256) void k_count_cnt(const int* __restrict__ dst,
                                                   const int* __restrict__ batch,
                                                   int* __restrict__ deg,
                                                   float* __restrict__ cnt)
{
    const int bid = blockIdx.x;
    if (bid < NEDGE / 256) {
        int e = bid * 256 + threadIdx.x;
        atomicAdd(&deg[dst[e]], 1);
    } else {
        int n = (bid - NEDGE / 256) * 256 + threadIdx.x;
        atomicAdd(&cnt[batch[n]], 1.f);
    }
}

// ---------------------------------------------------------------- scan + dis/invd (1 block, shuffle-based)
__global__ __launch_bounds__(1024) void k_scan(const int* __restrict__ deg,
                                               int* __restrict__ rowptr,
                                               int* __restrict__ cursor,
                                               float* __restrict__ dis,
                                               float* __restrict__ invd)
{
    __shared__ int wtot[16];
    const int t = threadIdx.x;
    const int lane = t & 63, wvid = t >> 6;
    int d[12]; int s = 0;
    #pragma unroll
    for (int m = 0; m < 12; ++m) { d[m] = deg[12 * t + m]; s += d[m]; }
    const int mysum = s;
    #pragma unroll
    for (int off = 1; off < 64; off <<= 1) {
        int u = __shfl_up(s, off);
        if (lane >= off) s += u;
    }
    if (lane == 63) wtot[wvid] = s;
    __syncthreads();
    if (t < 16) {
        int v = wtot[t];
        #pragma unroll
        for (int off = 1; off < 16; off <<= 1) {
            int u = __shfl_up(v, off);
            if (t >= off) v += u;
        }
        wtot[t] = v;
    }
    __syncthreads();
    int run = (wvid ? wtot[wvid - 1] : 0) + (s - mysum);   // block-exclusive prefix
    if (t == 0) rowptr[0] = 0;
    #pragma unroll
    for (int m = 0; m < 12; ++m) {
        const int i = 12 * t + m;
        cursor[i] = run;
        run += d[m];
        rowptr[i + 1] = run;
        float df = (float)(d[m] + 1);
        dis[i]  = rsqrtf(df);
        invd[i] = 1.f / df;
    }
}

// ---------------------------------------------------------------- CSR scatter
__global__ __launch_bounds__(256) void k_scatter(const int* __restrict__ src,
                                                 const int* __restrict__ dst,
                                                 int* __restrict__ cursor,
                                                 int* __restrict__ csr)
{
    int e = blockIdx.x * 256 + threadIdx.x;
    if (e < NEDGE) {
        int d = dst[e];
        int idx = atomicAdd(&cursor[d], 1);
        csr[idx] = src[e];
    }
}

// ---------------------------------------------------------------- aggregation BEFORE transform (pull)
// agg[n] = invd[n]*h[n] + sum_s dis[s]*dis[n]*h[s]
template <int F>
__global__ __launch_bounds__(256) void k_pull_a(
    const float* __restrict__ h, const int* __restrict__ rowptr,
    const int* __restrict__ csr, const float* __restrict__ dis,
    const float* __restrict__ invd, float* __restrict__ agg)
{
    const int npb = 256 / F;
    const int n = blockIdx.x * npb + threadIdx.x / F;
    const int f = threadIdx.x & (F - 1);
    const float dn = dis[n];
    float a0 = h[(size_t)n * F + f] * invd[n];
    float a1 = 0.f, a2 = 0.f, a3 = 0.f;
    int e = rowptr[n];
    const int e1 = rowptr[n + 1];
    for (; e + 3 < e1; e += 4) {
        int s0 = csr[e], s1 = csr[e + 1], s2 = csr[e + 2], s3 = csr[e + 3];
        a0 = fmaf(h[(size_t)s0 * F + f], dis[s0] * dn, a0);
        a1 = fmaf(h[(size_t)s1 * F + f], dis[s1] * dn, a1);
        a2 = fmaf(h[(size_t)s2 * F + f], dis[s2] * dn, a2);
        a3 = fmaf(h[(size_t)s3 * F + f], dis[s3] * dn, a3);
    }
    for (; e < e1; ++e) {
        int s0 = csr[e];
        a0 = fmaf(h[(size_t)s0 * F + f], dis[s0] * dn, a0);
    }
    agg[(size_t)n * F + f] = (a0 + a1) + (a2 + a3);
}

// ---------------------------------------------------------------- agg @ W + bias + relu (+pool)
template <int K, int POOL>
__global__ __launch_bounds__(256) void k_gemm_f(
    const float* __restrict__ in, const float* __restrict__ W,
    const float* __restrict__ bvec, float* __restrict__ out,
    const int* __restrict__ batch, float* __restrict__ pooled)
{
    __shared__ float hs[8][K];
    const int tid  = threadIdx.x;
    const int n0   = blockIdx.x * 8;
    const int j    = tid & 127;
    const int half = tid >> 7;

    #pragma unroll
    for (int it = 0; it < 8 * K / 256; ++it) {
        int idx = it * 256 + tid;
        int nn = idx / K, kk = idx & (K - 1);
        hs[nn][kk] = in[(size_t)(n0 + nn) * K + kk];
    }
    __syncthreads();

    float a[4];
    #pragma unroll
    for (int c = 0; c < 4; ++c) a[c] = bvec[j];

    for (int k4 = 0; k4 < K; k4 += 4) {
        float w0 = W[(k4 + 0) * F1 + j];
        float w1 = W[(k4 + 1) * F1 + j];
        float w2 = W[(k4 + 2) * F1 + j];
        float w3 = W[(k4 + 3) * F1 + j];
        #pragma unroll
        for (int c = 0; c < 4; ++c) {
            float4 hv = *(const float4*)&hs[half * 4 + c][k4];
            a[c] = fmaf(hv.x, w0, a[c]);
            a[c] = fmaf(hv.y, w1, a[c]);
            a[c] = fmaf(hv.z, w2, a[c]);
            a[c] = fmaf(hv.w, w3, a[c]);
        }
    }
    #pragma unroll
    for (int c = 0; c < 4; ++c) {
        float r = fmaxf(a[c], 0.f);
        int n = n0 + half * 4 + c;
        if (POOL) atomicAdd(&pooled[(size_t)batch[n] * F1 + j], r);
        else      out[(size_t)n * F1 + j] = r;
    }
}

// ---------------------------------------------------------------- final FC 128 -> 5
__global__ __launch_bounds__(128) void k_final(const float* __restrict__ pooled,
                                               const float* __restrict__ cnt,
                                               const float* __restrict__ fc_w,
                                               const float* __restrict__ fc_b,
                                               float* __restrict__ out)
{
    __shared__ float ps[F1];
    const int g = blockIdx.x, tid = threadIdx.x;
    float inv = 1.f / fmaxf(cnt[g], 1.f);
    ps[tid] = pooled[g * F1 + tid] * inv;
    __syncthreads();
    if (tid < 5) {
        float a = fc_b[tid];
        for (int f = 0; f < F1; ++f) a = fmaf(ps[f], fc_w[f * 5 + tid], a);
        out[g * 5 + tid] = a;
    }
}

// ---------------------------------------------------------------- launch
extern "C" void kernel_launch(void* const* d_in, const int* in_sizes, int n_in,
                              void* d_out, int out_size, void* d_ws, size_t ws_size,
                              hipStream_t stream)
{
    const float* x_raw = (const float*)d_in[0];
    const float* c1w   = (const float*)d_in[1];
    const float* c1b   = (const float*)d_in[2];
    const float* c2w   = (const float*)d_in[3];
    const float* c2b   = (const float*)d_in[4];
    const float* lw    = (const float*)d_in[5];
    const float* lb    = (const float*)d_in[6];
    const float* g1w   = (const float*)d_in[7];
    const float* g1b   = (const float*)d_in[8];
    const float* g2w   = (const float*)d_in[9];
    const float* g2b   = (const float*)d_in[10];
    const float* fcw   = (const float*)d_in[11];
    const float* fcb   = (const float*)d_in[12];
    const int*   ei    = (const int*)d_in[13];
    const int*   batch = (const int*)d_in[14];
    const int* src = ei;
    const int* dst = ei + NEDGE;

    float* ws = (float*)d_ws;
    float* h0     = ws + 0;                    // 786432  (12288 x 64)
    float* agg1   = ws + 786432;               // 786432
    float* h1     = ws + 1572864;              // 1572864 (12288 x 128)
    float* agg2   = ws + 3145728;              // 1572864
    float* dis    = ws + 4718592;              // 12288
    float* invd   = ws + 4730880;              // 12288
    float* pooled = ws + 4743168;              // 131072
    float* cnt    = ws + 4874240;              // 1024
    int*   deg    = (int*)(ws + 4875264);      // 12288
    int*   rowptr = (int*)(ws + 4887552);      // 12289 (+pad)
    int*   cursor = (int*)(ws + 4899844);      // 12288
    int*   csr    = (int*)(ws + 4912132);      // 196608

    float* out = (float*)d_out;

    hipMemsetAsync(deg, 0, N_NODES * sizeof(int), stream);
    hipMemsetAsync(pooled, 0, (size_t)(NGRAPH * F1 + NGRAPH) * sizeof(float), stream);

    k_encoder<<<N_NODES, 256, 0, stream>>>(x_raw, c1w, c1b, c2w, c2b, lw, lb, h0);
    k_count_cnt<<<NEDGE / 256 + N_NODES / 256, 256, 0, stream>>>(dst, batch, deg, cnt);
    k_scan<<<1, 1024, 0, stream>>>(deg, rowptr, cursor, dis, invd);
    k_scatter<<<NEDGE / 256, 256, 0, stream>>>(src, dst, cursor, csr);

    // GCN layer 1: aggregate (64-dim) then transform
    k_pull_a<F0><<<N_NODES / 4, 256, 0, stream>>>(h0, rowptr, csr, dis, invd, agg1);
    k_gemm_f<F0, 0><<<N_NODES / 8, 256, 0, stream>>>(agg1, g1w, g1b, h1, batch, pooled);

    // GCN layer 2: aggregate (128-dim) then transform + fused pool
    k_pull_a<F1><<<N_NODES / 2, 256, 0, stream>>>(h1, rowptr, csr, dis, invd, agg2);
    k_gemm_f<F1, 1><<<N_NODES / 8, 256, 0, stream>>>(agg2, g2w, g2b, nullptr, batch, pooled);

    k_final<<<NGRAPH, 128, 0, stream>>>(pooled, cnt, fcw, fcb, out);
}